// Round 2
// baseline (532.397 us; speedup 1.0000x reference)
//
#include <hip/hip_runtime.h>
#include <math.h>
#include <stdint.h>

#define B_ 4
#define T_ 2048
#define C_ 2048
#define NH 16
#define NKV 4
#define HD 128
#define NREP 4
#define KVC (NKV*HD)   // 512
#define QSTR 3072      // merged qkv row stride

typedef __attribute__((ext_vector_type(8))) __bf16 bf16x8;
typedef __attribute__((ext_vector_type(4))) float floatx4;

#define GLOBAL_AS __attribute__((address_space(1)))
#define LDS_AS __attribute__((address_space(3)))

__device__ __forceinline__ void gl2lds16(const unsigned short* g, unsigned short* l) {
  __builtin_amdgcn_global_load_lds((const GLOBAL_AS unsigned int*)g,
                                   (LDS_AS unsigned int*)l, 16, 0, 0);
}

__device__ __forceinline__ float b2f(unsigned short u) {
  union { unsigned int i; float f; } v; v.i = ((unsigned int)u) << 16; return v.f;
}
__device__ __forceinline__ unsigned short f2b(float f) {
  union { float f; unsigned int i; } v; v.f = f;
  unsigned int r = v.i + 0x7fffu + ((v.i >> 16) & 1u);
  return (unsigned short)(r >> 16);
}

// ---------------- fp32 -> bf16 convert ----------------
__global__ void cvt_bf16_kernel(const float* __restrict__ X,
                                unsigned short* __restrict__ Y, int n) {
  int i = (blockIdx.x * 256 + threadIdx.x) * 4;
  if (i >= n) return;
  float4 v = *(const float4*)(X + i);
  ushort4 o;
  o.x = f2b(v.x); o.y = f2b(v.y); o.z = f2b(v.z); o.w = f2b(v.w);
  *(ushort4*)(Y + i) = o;
}

// ---------------- W (KxN fp32) -> Wt (NxK bf16) ----------------
__global__ void transpose_cvt_kernel(const float* __restrict__ W,
                                     unsigned short* __restrict__ Wt,
                                     int K, int N) {
  __shared__ float tile[32][33];
  int n = blockIdx.x * 32 + threadIdx.x;
  int kbase = blockIdx.y * 32;
  #pragma unroll
  for (int i = 0; i < 32; i += 8)
    tile[threadIdx.y + i][threadIdx.x] = W[(size_t)(kbase + threadIdx.y + i) * N + n];
  __syncthreads();
  int k = kbase + threadIdx.x;
  int nb = blockIdx.x * 32;
  #pragma unroll
  for (int i = 0; i < 32; i += 8)
    Wt[(size_t)(nb + threadIdx.y + i) * K + k] = f2b(tile[threadIdx.x][threadIdx.y + i]);
}

// ------- V part of qkv (rows stride QSTR) -> Vt (B,NKV,HD,T bf16) -------
__global__ void transpose_v_kernel(const unsigned short* __restrict__ V,
                                   unsigned short* __restrict__ Vt) {
  __shared__ unsigned short tile[32][33];
  int d0 = blockIdx.x * 32;
  int sg = blockIdx.y * 32;          // global row in (B*T)
  int b = sg >> 11;                  // / T_
  int s0 = sg & (T_ - 1);
  #pragma unroll
  for (int i = 0; i < 32; i += 8)
    tile[threadIdx.y + i][threadIdx.x] =
        V[(size_t)(sg + threadIdx.y + i) * QSTR + d0 + threadIdx.x];
  __syncthreads();
  #pragma unroll
  for (int i = 0; i < 32; i += 8) {
    int d = d0 + threadIdx.y + i;
    int g = d >> 7, dl = d & 127;
    Vt[((size_t)(b * NKV + g) * HD + dl) * T_ + s0 + threadIdx.x] =
        tile[threadIdx.x][threadIdx.y + i];
  }
}

// =====================================================================
// 256x256 8-phase bf16 GEMM (T2 swizzled LDS + T3/T4 counted vmcnt + T5)
// K-tile = 64, k-split half-tiles {Ak0,Bk0,Ak1,Bk1} of 16 KB each.
// LDS: 2 buffers x 64 KB = 128 KiB. 512 threads = 8 waves (2M x 4N).
// Pipeline: phase p of tile t stages half p of tile t+1; vmcnt(4) at
// p1 guards this tile's kk=1 halves, vmcnt(4) at p3 guards next tile's
// kk=0 halves. Outstanding never drains below 4 loads in steady state.
// LDS chunk placement: chunk (row,kg) at slot kg ^ ((row>>1)&3) ->
// conflict-free ds_read_b128 (each lane-octet covers all 32 banks once).
// Achieved by permuting the per-lane GLOBAL source; LDS dest stays
// linear (global_load_lds requirement, rule 21).
// =====================================================================
template<int STORE_BF16>
__global__ __launch_bounds__(512, 2) void gemm256_bt(
    const unsigned short* __restrict__ A,   // M x K bf16
    const unsigned short* __restrict__ Bt,  // N x K bf16
    void* __restrict__ Cout,                // M x N (bf16 or f32)
    int M, int N, int K)
{
  __shared__ unsigned short Lds[65536];   // 128 KiB

  int tid = threadIdx.x;

  // T1: XCD swizzle (grids are multiples of 8: 384 / 256)
  int nbx = gridDim.x;
  int nwg = nbx * gridDim.y;
  int orig = blockIdx.y * nbx + blockIdx.x;
  int cpx = nwg >> 3;
  int swz = (orig & 7) * cpx + (orig >> 3);
  int m0 = (swz % nbx) * 256;
  int n0 = (swz / nbx) * 256;

  int wave = tid >> 6, lane = tid & 63;
  int fr = lane & 15, kg = lane >> 4;
  int slot = kg ^ ((fr >> 1) & 3);          // swizzled 16B-slot for ds_read
  int wm_off = (wave >> 2) * 128;           // wave's M half
  int wn_off = (wave & 3) * 64;             // wave's N quarter

  // staging coords: lane covers global chunk (row = wave*16 + lane/4, kg = kgs)
  // so that linear LDS dest realizes the slot swizzle above
  int rowoff = wave * 16 + (lane >> 2);
  int kgs = (lane & 3) ^ ((lane >> 3) & 3);
  const unsigned short* Asrc = A  + (size_t)(m0 + rowoff) * K + kgs * 8;
  const unsigned short* Bsrc = Bt + (size_t)(n0 + rowoff) * K + kgs * 8;
  size_t rstep = (size_t)128 * K;           // second staging round: rows +128

  // LDS read bases (ushort units); block layout per buffer:
  //   Ak0 @0, Bk0 @8192, Ak1 @16384, Bk1 @24576; buffers stride 32768
  int abase = (wm_off + fr) * 32 + slot * 8;
  int bbase = 8192 + (wn_off + fr) * 32 + slot * 8;

  floatx4 acc[8][4];
  #pragma unroll
  for (int i = 0; i < 8; i++)
    #pragma unroll
    for (int j = 0; j < 4; j++)
      acc[i][j] = (floatx4){0.f, 0.f, 0.f, 0.f};

  int nt = K >> 6;

  // stage half (kkh, isB) of tile tn into buffer tn&1 (2 x global_load_lds)
  #define STAGE_HALF(tn, kkh, isB) do {                                        \
    const unsigned short* s_ = ((isB) ? Bsrc : Asrc) + (size_t)(tn) * 64 + (kkh) * 32; \
    unsigned short* d_ = &Lds[(((tn) & 1) << 15) + ((kkh) << 14) + ((isB) << 13) + (wave << 9)]; \
    gl2lds16(s_, d_);                                                          \
    gl2lds16(s_ + rstep, d_ + 4096);                                           \
  } while (0)

  // prologue: all 4 halves of tile 0; wait until Ak0,Bk0 landed (Ak1,Bk1 in flight)
  STAGE_HALF(0, 0, 0); STAGE_HALF(0, 0, 1); STAGE_HALF(0, 1, 0); STAGE_HALF(0, 1, 1);
  asm volatile("s_waitcnt vmcnt(4)" ::: "memory");
  __builtin_amdgcn_s_barrier();

  bf16x8 bfrag[4];
  for (int t = 0; t < nt; ++t) {
    int cb = (t & 1) << 15;
    int more = (t + 1 < nt);
    #pragma unroll
    for (int p = 0; p < 4; ++p) {
      const int kkc = p >> 1, mhc = p & 1;
      // ds-load register subtiles (B shared across the two m-half phases)
      if (mhc == 0) {
        #pragma unroll
        for (int j = 0; j < 4; ++j) {
          union { uint4 u; bf16x8 v; } tb;
          tb.u = *(const uint4*)&Lds[cb + bbase + (kkc << 14) + j * 512];
          bfrag[j] = tb.v;
        }
      }
      bf16x8 af[4];
      #pragma unroll
      for (int i = 0; i < 4; ++i) {
        union { uint4 u; bf16x8 v; } ta;
        ta.u = *(const uint4*)&Lds[cb + abase + (kkc << 14) + (mhc * 4 + i) * 512];
        af[i] = ta.v;
      }
      // stage half p of tile t+1 (order Ak0,Bk0,Ak1,Bk1 matches consume order)
      if (more) STAGE_HALF(t + 1, kkc, mhc);
      // counted waits (T4): never drain to 0 in steady state
      if (p == 1) {
        if (more) asm volatile("s_waitcnt vmcnt(4)" ::: "memory");
        else      asm volatile("s_waitcnt vmcnt(0)" ::: "memory");
      } else if (p == 3) {
        if (more) asm volatile("s_waitcnt vmcnt(4)" ::: "memory");
      }
      __builtin_amdgcn_s_barrier();
      asm volatile("s_waitcnt lgkmcnt(0)" ::: "memory");
      __builtin_amdgcn_s_setprio(1);                       // T5
      #pragma unroll
      for (int i = 0; i < 4; ++i)
        #pragma unroll
        for (int j = 0; j < 4; ++j)
          acc[mhc * 4 + i][j] =
              __builtin_amdgcn_mfma_f32_16x16x32_bf16(af[i], bfrag[j], acc[mhc * 4 + i][j], 0, 0, 0);
      __builtin_amdgcn_s_setprio(0);
      __builtin_amdgcn_s_barrier();
    }
  }
  #undef STAGE_HALF

  // epilogue: C layout col=lane&15, row=(lane>>4)*4+reg (m89/m91 verified)
  int erow = kg * 4;
  #pragma unroll
  for (int i = 0; i < 8; ++i)
    #pragma unroll
    for (int j = 0; j < 4; ++j) {
      int gm = m0 + wm_off + i * 16 + erow;
      int gn = n0 + wn_off + j * 16 + fr;
      #pragma unroll
      for (int r = 0; r < 4; ++r) {
        float v = acc[i][j][r];
        if (STORE_BF16)
          ((unsigned short*)Cout)[(size_t)(gm + r) * N + gn] = f2b(v);
        else
          ((float*)Cout)[(size_t)(gm + r) * N + gn] = v;
      }
    }
}

// ---------------- RoPE (in-place on bf16 with row stride) ----------------
__global__ void rope_kernel(unsigned short* __restrict__ X,
                            const float* __restrict__ FC, int nheads, int stride) {
  long long idx = (long long)blockIdx.x * 256 + threadIdx.x;
  int p = (int)(idx & (HD / 2 - 1));
  long long t1 = idx >> 6;
  int h = (int)(t1 % nheads);
  long long row = t1 / nheads;
  int t = (int)(row & (T_ - 1));
  float c = FC[((size_t)t * (HD / 2) + p) * 2 + 0];
  float s = FC[((size_t)t * (HD / 2) + p) * 2 + 1];
  unsigned short* ptr = X + row * (size_t)stride + h * HD + 2 * p;
  float a = b2f(ptr[0]), b = b2f(ptr[1]);
  ptr[0] = f2b(a * c - b * s);
  ptr[1] = f2b(a * s + b * c);
}

// ------- flash attention, MFMA, fixed-max softmax, 32 q-rows/wave -------
#define ABR 128    // q rows per block (4 waves x 32)
#define ABC 64     // kv cols per iter
#define KLD 136    // K-tile stride in KPs (64 rows)
#define VLD 72     // Vs stride
#define PLD 72     // P stride in KPs (128 rows)

__global__ __launch_bounds__(256, 3) void attn_mfma_kernel(
    const unsigned short* __restrict__ Q,   // qkv base, stride QSTR, roped
    const unsigned short* __restrict__ Kg,  // qkv+2048, stride QSTR, roped
    const unsigned short* __restrict__ Vt,  // (B*NKV) x HD x T
    unsigned short* __restrict__ O)         // (B*T) x 2048
{
  __shared__ unsigned short KPs[128 * PLD];  // 18432 B: K tile (64xKLD) / P (128xPLD)
  __shared__ unsigned short Vs[HD * VLD];    // 18432 B

  int bh = blockIdx.x;
  int qt = (int)(gridDim.y - 1 - blockIdx.y);   // heavy blocks dispatch first
  int b = bh >> 4, h = bh & 15, g = h >> 2;
  int tid = threadIdx.x, wave = tid >> 6, lane = tid & 63;
  int fr = lane & 15, kg = lane >> 4, erow = 4 * kg;

  // Q A-fragments, 2 row-tiles of 16 per wave (32 q-rows/wave)
  bf16x8 qf[2][4];
  #pragma unroll
  for (int rt = 0; rt < 2; rt++) {
    const unsigned short* qrow =
        Q + (size_t)(b * T_ + qt * ABR + wave * 32 + rt * 16 + fr) * QSTR + h * HD;
    #pragma unroll
    for (int kk = 0; kk < 4; kk++) {
      union { uint4 u; bf16x8 v; } t;
      t.u = *(const uint4*)(qrow + kk * 32 + kg * 8);
      qf[rt][kk] = t.v;
    }
  }

  floatx4 oacc[2][8];
  #pragma unroll
  for (int rt = 0; rt < 2; rt++)
    #pragma unroll
    for (int d = 0; d < 8; d++) oacc[rt][d] = (floatx4){0.f, 0.f, 0.f, 0.f};
  float rsum[2][4];
  #pragma unroll
  for (int rt = 0; rt < 2; rt++)
    #pragma unroll
    for (int r = 0; r < 4; r++) rsum[rt][r] = 0.f;

  const float scale = 0.08838834764831845f;
  const float MOFF = 9.0f;   // fixed softmax offset; S*scale stays well below 9

  size_t krow0 = (size_t)(b * T_) * QSTR + g * HD;
  size_t vbase = ((size_t)(b * NKV + g) * HD) * T_;
  int q0 = qt * ABR + wave * 32;
  int nit = 2 * qt + 2;

  int sr = tid >> 2, kc4 = (tid & 3) * 8;   // K staging coords
  int vr = tid >> 1, vc = (tid & 1) * 8;    // V staging coords

  for (int it = 0; it < nit; it++) {
    int s0 = it * ABC;
    __syncthreads();   // prior iter's KPs(P)/Vs reads complete
    {
      const unsigned short* src = Kg + krow0 + (size_t)(s0 + sr) * QSTR;
      #pragma unroll
      for (int c = 0; c < 4; c++)
        *(uint4*)&KPs[sr * KLD + kc4 + c * 32] = *(const uint4*)(src + kc4 + c * 32);
      const unsigned short* vsrc = Vt + vbase + (size_t)vr * T_ + s0;
      #pragma unroll
      for (int c = 0; c < 4; c++)
        *(uint4*)&Vs[vr * VLD + vc + c * 16] = *(const uint4*)(vsrc + vc + c * 16);
    }
    __syncthreads();   // tiles visible

    // S = Q K^T : kf shared across both row-tiles
    floatx4 scr[2][4];
    #pragma unroll
    for (int rt = 0; rt < 2; rt++)
      #pragma unroll
      for (int t = 0; t < 4; t++) scr[rt][t] = (floatx4){0.f, 0.f, 0.f, 0.f};
    __builtin_amdgcn_s_setprio(1);   // T5: blocks at different phases co-resident
    #pragma unroll
    for (int kk = 0; kk < 4; kk++) {
      #pragma unroll
      for (int t = 0; t < 4; t++) {
        union { uint4 u; bf16x8 v; } kf;
        kf.u = *(const uint4*)&KPs[(t * 16 + fr) * KLD + kk * 32 + kg * 8];
        scr[0][t] = __builtin_amdgcn_mfma_f32_16x16x32_bf16(qf[0][kk], kf.v, scr[0][t], 0, 0, 0);
        scr[1][t] = __builtin_amdgcn_mfma_f32_16x16x32_bf16(qf[1][kk], kf.v, scr[1][t], 0, 0, 0);
      }
    }
    __builtin_amdgcn_s_setprio(0);

    // mask + exp(S*scale - MOFF), accumulate per-lane row partial sums
    #pragma unroll
    for (int t = 0; t < 4; t++) {
      int s_g = s0 + t * 16 + fr;
      #pragma unroll
      for (int rt = 0; rt < 2; rt++)
        #pragma unroll
        for (int r = 0; r < 4; r++) {
          int qrow = q0 + rt * 16 + erow + r;
          float p = (s_g <= qrow) ? __expf(scr[rt][t][r] * scale - MOFF) : 0.f;
          scr[rt][t][r] = p;
          rsum[rt][r] += p;
        }
    }
    __syncthreads();   // all waves done reading KPs as K

    // P -> KPs (PLD layout; each wave writes its own 32 rows)
    #pragma unroll
    for (int rt = 0; rt < 2; rt++)
      #pragma unroll
      for (int t = 0; t < 4; t++)
        #pragma unroll
        for (int r = 0; r < 4; r++)
          KPs[(wave * 32 + rt * 16 + erow + r) * PLD + t * 16 + fr] = f2b(scr[rt][t][r]);

    // PV: pf from own strip (in-order DS per wave, no barrier), vf shared across rt
    bf16x8 pf[2][2];
    #pragma unroll
    for (int rt = 0; rt < 2; rt++)
      #pragma unroll
      for (int kk = 0; kk < 2; kk++) {
        union { uint4 u; bf16x8 v; } t;
        t.u = *(const uint4*)&KPs[(wave * 32 + rt * 16 + fr) * PLD + kk * 32 + kg * 8];
        pf[rt][kk] = t.v;
      }
    __builtin_amdgcn_s_setprio(1);   // T5 on the PV cluster
    #pragma unroll
    for (int d = 0; d < 8; d++)
      #pragma unroll
      for (int kk = 0; kk < 2; kk++) {
        union { uint4 u; bf16x8 v; } vf;
        vf.u = *(const uint4*)&Vs[(d * 16 + fr) * VLD + kk * 32 + kg * 8];
        oacc[0][d] = __builtin_amdgcn_mfma_f32_16x16x32_bf16(pf[0][kk], vf.v, oacc[0][d], 0, 0, 0);
        oacc[1][d] = __builtin_amdgcn_mfma_f32_16x16x32_bf16(pf[1][kk], vf.v, oacc[1][d], 0, 0, 0);
      }
    __builtin_amdgcn_s_setprio(0);
  }

  // reduce row sums across the 16 cols held by fr-group (once, at end)
  #pragma unroll
  for (int rt = 0; rt < 2; rt++)
    #pragma unroll
    for (int r = 0; r < 4; r++) {
      float s = rsum[rt][r];
      s += __shfl_xor(s, 1); s += __shfl_xor(s, 2);
      s += __shfl_xor(s, 4); s += __shfl_xor(s, 8);
      rsum[rt][r] = s;
    }

  #pragma unroll
  for (int rt = 0; rt < 2; rt++)
    #pragma unroll
    for (int r = 0; r < 4; r++) {
      float inv = 1.f / rsum[rt][r];
      size_t orow =
          (size_t)(b * T_ + qt * ABR + wave * 32 + rt * 16 + erow + r) * C_ + h * HD;
      #pragma unroll
      for (int d = 0; d < 8; d++)
        O[orow + d * 16 + fr] = f2b(oacc[rt][d][r] * inv);
    }
}

// ---------------- launcher ----------------
extern "C" void kernel_launch(void* const* d_in, const int* in_sizes, int n_in,
                              void* d_out, int out_size, void* d_ws, size_t ws_size,
                              hipStream_t stream) {
  (void)in_sizes; (void)n_in; (void)out_size; (void)ws_size;
  const float* x  = (const float*)d_in[0];
  const float* fc = (const float*)d_in[1];
  const float* wq = (const float*)d_in[2];
  const float* wk = (const float*)d_in[3];
  const float* wv = (const float*)d_in[4];
  const float* wo = (const float*)d_in[5];
  float* out = (float*)d_out;

  char* ws = (char*)d_ws;
  unsigned short* xb   = (unsigned short*)(ws);                 // 32 MB
  unsigned short* qkv  = (unsigned short*)(ws + 33554432);      // 48 MB (M x 3072)
  unsigned short* wqT  = (unsigned short*)(ws + 83886080);      // 8 MB (merged Wt rows 0..2047)
  unsigned short* wkT  = (unsigned short*)(ws + 92274688);      // 2 MB (rows 2048..2559)
  unsigned short* wvT  = (unsigned short*)(ws + 94371840);      // 2 MB (rows 2560..3071)
  unsigned short* woT  = (unsigned short*)(ws + 96468992);      // 8 MB (total 100 MiB)
  unsigned short* vt   = wqT;  // reuse: merged weights dead after QKV GEMM
  unsigned short* yb   = xb;   // reuse: x dead after QKV GEMM

  int nx = B_ * T_ * C_;
  cvt_bf16_kernel<<<nx / 4 / 256, 256, 0, stream>>>(x, xb, nx);
  transpose_cvt_kernel<<<dim3(C_ / 32, C_ / 32), dim3(32, 8), 0, stream>>>(wq, wqT, C_, C_);
  transpose_cvt_kernel<<<dim3(KVC / 32, C_ / 32), dim3(32, 8), 0, stream>>>(wk, wkT, C_, KVC);
  transpose_cvt_kernel<<<dim3(KVC / 32, C_ / 32), dim3(32, 8), 0, stream>>>(wv, wvT, C_, KVC);
  transpose_cvt_kernel<<<dim3(C_ / 32, C_ / 32), dim3(32, 8), 0, stream>>>(wo, woT, C_, C_);

  int M = B_ * T_;
  // merged QKV GEMM: [M,2048] x [3072,2048]^T -> qkv [M,3072]  (256^2 8-phase)
  gemm256_bt<1><<<dim3(M / 256, QSTR / 256), 512, 0, stream>>>(xb, wqT, qkv, M, QSTR, C_);

  long long qp = (long long)B_ * T_ * NH * (HD / 2);
  rope_kernel<<<(unsigned)(qp / 256), 256, 0, stream>>>(qkv, fc, NH, QSTR);
  long long kp = (long long)B_ * T_ * NKV * (HD / 2);
  rope_kernel<<<(unsigned)(kp / 256), 256, 0, stream>>>(qkv + 2048, fc, NKV, QSTR);

  // V part -> Vt (d-major), overlays dead weights
  transpose_v_kernel<<<dim3(KVC / 32, B_ * T_ / 32), dim3(32, 8), 0, stream>>>(qkv + 2560, vt);

  attn_mfma_kernel<<<dim3(B_ * NH, T_ / ABR), 256, 0, stream>>>(qkv, qkv + 2048, vt, yb);

  // WO GEMM: [M,2048] x [2048,2048]^T -> out f32  (256^2 8-phase)
  gemm256_bt<0><<<dim3(M / 256, C_ / 256), 512, 0, stream>>>(yb, woT, out, M, C_, C_);
}